// Round 5
// baseline (1446.386 us; speedup 1.0000x reference)
//
#include <hip/hip_runtime.h>
#include <stdint.h>

typedef unsigned short u16;
typedef __attribute__((ext_vector_type(8))) short short8;
typedef __attribute__((ext_vector_type(4))) short s16x4;
typedef __attribute__((ext_vector_type(4))) float f32x4;

#define NTOK 1024
#define CDIM 512
#define NG 32

#define GLOAD_LDS16(gptr, lptr)                                                              \
  __builtin_amdgcn_global_load_lds((const __attribute__((address_space(1))) unsigned int*)(gptr), \
                                   (__attribute__((address_space(3))) unsigned int*)(lptr), 16, 0, 0)

__device__ __forceinline__ u16 f2bf(float f) {
  union { float f; uint32_t u; } v; v.f = f;
  uint32_t r = v.u + 0x7fffu + ((v.u >> 16) & 1u);
  return (u16)(r >> 16);
}

__device__ __forceinline__ float bf2f(u16 b) {
  union { uint32_t u; float f; } v; v.u = ((uint32_t)b) << 16;
  return v.f;
}

// ---------------- weight fp32 -> bf16 (+ concat qkv bias) ----------------
__global__ __launch_bounds__(256) void wconv(const float* __restrict__ wq, const float* __restrict__ wk,
                                             const float* __restrict__ wv, const float* __restrict__ wo,
                                             const float* __restrict__ bq, const float* __restrict__ bk,
                                             const float* __restrict__ bv,
                                             u16* __restrict__ out, float* __restrict__ bqkv) {
  int i = blockIdx.x * 256 + threadIdx.x;
  out[i]          = f2bf(wq[i]);
  out[262144 + i] = f2bf(wk[i]);
  out[524288 + i] = f2bf(wv[i]);
  out[786432 + i] = f2bf(wo[i]);
  if (i < 512) bqkv[i] = bq[i];
  else if (i < 1024) bqkv[i] = bk[i - 512];
  else if (i < 1536) bqkv[i] = bv[i - 1024];
}

// ---------------- GroupNorm stats: one block per (b,g) ----------------
__global__ __launch_bounds__(256) void gn_stats(const float* __restrict__ x,
                                                float* __restrict__ mean_o, float* __restrict__ rstd_o) {
  int bg = blockIdx.x;
  const float4* base = (const float4*)(x + (size_t)bg * 16384);
  float s = 0.f, ss = 0.f;
  for (int i = threadIdx.x; i < 4096; i += 256) {
    float4 v = base[i];
    s  += v.x + v.y + v.z + v.w;
    ss += v.x * v.x + v.y * v.y + v.z * v.z + v.w * v.w;
  }
#pragma unroll
  for (int d = 1; d < 64; d <<= 1) { s += __shfl_xor(s, d); ss += __shfl_xor(ss, d); }
  __shared__ float as[4], as2[4];
  int w = threadIdx.x >> 6;
  if ((threadIdx.x & 63) == 0) { as[w] = s; as2[w] = ss; }
  __syncthreads();
  if (threadIdx.x == 0) {
    float S = as[0] + as[1] + as[2] + as[3];
    float SS = as2[0] + as2[1] + as2[2] + as2[3];
    float m = S * (1.f / 16384.f);
    float var = SS * (1.f / 16384.f) - m * m;
    mean_o[bg] = m;
    rstd_o[bg] = rsqrtf(var + 1e-5f);
  }
}

// ---------------- GN apply + transpose -> h[(b*1024+n)][c] bf16 ----------------
__global__ __launch_bounds__(256) void gn_apply(const float* __restrict__ x,
                                                const float* __restrict__ mean_, const float* __restrict__ rstd_,
                                                const float* __restrict__ gsc, const float* __restrict__ gbi,
                                                u16* __restrict__ h) {
  int n0 = blockIdx.x * 64, c0 = blockIdx.y * 64, b = blockIdx.z;
  __shared__ u16 t[64][65];
  int tid = threadIdx.x;
  int nl4 = (tid & 15) * 4;
  int clb = tid >> 4;
#pragma unroll
  for (int p = 0; p < 4; ++p) {
    int cl = p * 16 + clb;
    int c = c0 + cl;
    int g = c >> 4;
    float m = mean_[b * NG + g], rs = rstd_[b * NG + g];
    float sc = gsc[c] * rs, bi = gbi[c] - m * sc;
    float4 v = *(const float4*)(x + ((size_t)b * CDIM + c) * NTOK + n0 + nl4);
    t[cl][nl4 + 0] = f2bf(v.x * sc + bi);
    t[cl][nl4 + 1] = f2bf(v.y * sc + bi);
    t[cl][nl4 + 2] = f2bf(v.z * sc + bi);
    t[cl][nl4 + 3] = f2bf(v.w * sc + bi);
  }
  __syncthreads();
  int nl = tid >> 3;
  int cc = (tid & 7) * 8;
#pragma unroll
  for (int p = 0; p < 2; ++p) {
    int n = nl + p * 32;
    short8 o;
#pragma unroll
    for (int i = 0; i < 8; ++i) o[i] = (short)t[cc + i][n];
    *(short8*)(h + (size_t)(b * NTOK + n0 + n) * CDIM + c0 + cc) = o;
  }
}

// ---------------- GEMM 256x256 tile, 8 waves, BK=32, A[3]/B[2] buffers (80KB LDS) ----------------
// D[M][N] = A[M][K] * B[N][K]^T, row strides Ka/Kb (u16), K = nkt*32.
// 80KB LDS (vs 128KB at BK=64/2buf) -> 2 blocks/CU: co-resident block overlaps this block's
// epilogue stores and prefetch waits (m114 mechanism; at 1 block/CU both were dead time).
// 3-buffer A restores 4-phase prefetch lookahead; B gets 3 phases. vmcnt(4) per K-tile.
// Schedule per tile t (bufA pa=t%3, bufB pb=t&1):
//   P1: read af[i0-3](pa), bfr[j0-3](pb); stage A(t+2)->pa2; BAR; 16 MFMA; BAR
//   P2: read af[i4-7](pa);               stage B(t+2)->pb;  BAR; 16 MFMA; vmcnt(4); BAR
// Legality: A(t+2) targets buf of A(t-1), fully read at P2(t-1); B(t+2) targets buf of B(t),
// fully read at P1(t) (stage issued after P1's closing barrier). 64B row stride makes a wave's
// fragment read a contiguous 1KB block -> inherently bank-balanced, no swizzle needed.
// Epilogue: LDS-bounce -> coalesced short8/float4 line stores (round-4 win, unchanged).
// MODE 5: fused qkv. gc<1024 -> qk[gr][1024]+gc (+bias); gc>=1024 -> vT outb2[bt][ch][tok] (+bias)
// MODE 2: out fp32 [bt][gr][nn] + bias[gr] + resid   (o proj; M=ch, N=tokens)
// MODE 3: out bf16 [(z*1024+gr)][1024]+gc            (QK^T batched)
// MODE 4: out bf16 [((batch0+z)*1024+gr)][512]+gc    (PV batched)
template <int MODE>
__device__ __forceinline__ void gemm_body(const u16* __restrict__ A, const u16* __restrict__ B,
                                          const float* __restrict__ bias, u16* __restrict__ outb,
                                          u16* __restrict__ outb2,
                                          float* __restrict__ outf, const float* __restrict__ resid,
                                          int Ka, int Kb, int nkt,
                                          size_t strideA, size_t strideB, int batch0) {
  // XCD-chunked bijective swizzle (all launches have nwg % 8 == 0)
  int nx = gridDim.x, ny = gridDim.y;
  int nwg = nx * ny * gridDim.z;
  int id = blockIdx.x + nx * (blockIdx.y + ny * blockIdx.z);
  int cpx = nwg >> 3;
  int sw = (id & 7) * cpx + (id >> 3);
  int bx = sw % nx; int t_ = sw / nx;
  int by = t_ % ny; int z = t_ / ny;

  const u16* Amat = A + (size_t)z * strideA;
  const u16* Bmat = B + (size_t)z * strideB;
  int n0 = bx * 256, m0 = by * 256;
  __shared__ __align__(16) u16 SH[40960];   // 80KB: A bufs [3][8192] | B bufs [2][8192] @24576
  int tid = threadIdx.x;
  int l = tid & 63, wid = tid >> 6;
  int lr = l & 15, lh = l >> 4;
  int wm = (wid >> 2) * 128;     // 2 wave-rows x 4 wave-cols; per-wave 128x64 out
  int wn = (wid & 3) * 64;

  f32x4 acc[8][4];
#pragma unroll
  for (int i = 0; i < 8; ++i)
#pragma unroll
    for (int j = 0; j < 4; ++j) acc[i][j] = (f32x4){0.f, 0.f, 0.f, 0.f};

  short8 af[4];   // current i-half A fragments
  short8 bfr[4];  // j0-3 B fragments, live P1->P2

  // staging: 256 rows x 32 cols bf16 = 16KB per matrix per K-tile; thread t covers rows
  // (t>>2) and (t>>2)+128, 16B chunk (t&3). LDS dest offset = 16*lane (linear, DMA-legal).
  int sr = tid >> 2, sc4 = tid & 3;
  const u16* Ag0 = Amat + (size_t)(m0 + sr) * Ka + sc4 * 8;
  const u16* Ag1 = Ag0 + (size_t)128 * Ka;
  const u16* Bg0 = Bmat + (size_t)(n0 + sr) * Kb + sc4 * 8;
  const u16* Bg1 = Bg0 + (size_t)128 * Kb;
  u16* Al0 = SH + sr * 32 + sc4 * 8;
  u16* Bl0 = SH + 24576 + sr * 32 + sc4 * 8;

#define STAGE_A(bufsel, ktv)                                              \
  {                                                                       \
    GLOAD_LDS16(Ag0 + (ktv) * 32, Al0 + (bufsel) * 8192);                 \
    GLOAD_LDS16(Ag1 + (ktv) * 32, Al0 + (bufsel) * 8192 + 4096);          \
  }
#define STAGE_B(bufsel, ktv)                                              \
  {                                                                       \
    GLOAD_LDS16(Bg0 + (ktv) * 32, Bl0 + (bufsel) * 8192);                 \
    GLOAD_LDS16(Bg1 + (ktv) * 32, Bl0 + (bufsel) * 8192 + 4096);          \
  }

#define READ_AF(ihalf, bufsel)                                                        \
  _Pragma("unroll") for (int i_ = 0; i_ < 4; ++i_) {                                  \
    int row_ = wm + (ihalf) * 64 + i_ * 16 + lr;                                      \
    af[i_] = *(const short8*)(SH + (bufsel) * 8192 + row_ * 32 + lh * 8);             \
  }

#define READ_BF(bufsel)                                                               \
  _Pragma("unroll") for (int j_ = 0; j_ < 4; ++j_) {                                  \
    int row_ = wn + j_ * 16 + lr;                                                     \
    bfr[j_] = *(const short8*)(SH + 24576 + (bufsel) * 8192 + row_ * 32 + lh * 8);    \
  }

#define MFMA_H(ihalf)                                                                 \
  _Pragma("unroll") for (int i_ = 0; i_ < 4; ++i_)                                    \
    _Pragma("unroll") for (int j_ = 0; j_ < 4; ++j_)                                  \
      acc[(ihalf) * 4 + i_][j_] = __builtin_amdgcn_mfma_f32_16x16x32_bf16(            \
          af[i_], bfr[j_], acc[(ihalf) * 4 + i_][j_], 0, 0, 0);

#define PBAR() __builtin_amdgcn_s_barrier()

  // Prologue: tiles 0 and 1 staged; wait for tile 0 (first 4 loads), tile 1 stays in flight.
  STAGE_A(0, 0);
  STAGE_B(0, 0);
  STAGE_A(1, 1);
  STAGE_B(1, 1);
  asm volatile("s_waitcnt vmcnt(4)");
  __builtin_amdgcn_sched_barrier(0);
  PBAR();

  int pa = 0, pb = 0, pa2 = 2;
  for (int t = 0; t < nkt; ++t) {
    const bool more = t < nkt - 2;   // uniform
    // P1
    READ_AF(0, pa);
    READ_BF(pb);
    if (more) STAGE_A(pa2, t + 2);
    PBAR();
    __builtin_amdgcn_s_setprio(1);
    MFMA_H(0);
    __builtin_amdgcn_s_setprio(0);
    PBAR();
    // P2
    READ_AF(1, pa);
    if (more) STAGE_B(pb, t + 2);
    PBAR();
    __builtin_amdgcn_s_setprio(1);
    MFMA_H(1);
    __builtin_amdgcn_s_setprio(0);
    if (more) { asm volatile("s_waitcnt vmcnt(4)"); }
    else if (t == nkt - 2) { asm volatile("s_waitcnt vmcnt(0)"); }
    __builtin_amdgcn_sched_barrier(0);
    PBAR();
    pa = (pa == 2) ? 0 : pa + 1;
    pa2 = (pa2 == 2) ? 0 : pa2 + 1;
    pb ^= 1;
  }

  // ---------------- epilogue: LDS-bounce -> coalesced line stores ----------------
  __syncthreads();  // K-loop fully done; SH reusable as scratch
  const int gr0 = m0 + wm, gc0 = n0 + wn;
  u16* eb = SH + wid * 4352;             // per-wave [64][68] u16 scratch (8*8704B = 69.6KB)

  if constexpr (MODE == 5) {
    float bj[4];
#pragma unroll
    for (int j = 0; j < 4; ++j) bj[j] = bias[gc0 + j * 16 + lr];
    if (n0 < 1024) {
      // qk part: row-major [32768][1024]
#pragma unroll
      for (int pass = 0; pass < 2; ++pass) {
#pragma unroll
        for (int i2 = 0; i2 < 4; ++i2)
#pragma unroll
          for (int j = 0; j < 4; ++j)
#pragma unroll
            for (int r = 0; r < 4; ++r)
              eb[(i2 * 16 + lh * 4 + r) * 68 + j * 16 + lr] =
                  f2bf(acc[pass * 4 + i2][j][r] + bj[j]);
        asm volatile("s_waitcnt lgkmcnt(0)");
        __builtin_amdgcn_sched_barrier(0);
#pragma unroll
        for (int t = 0; t < 8; ++t) {
          int row = t * 8 + (l >> 3), c8 = (l & 7) * 8;
          s16x4 lo = *(const s16x4*)(eb + row * 68 + c8);
          s16x4 hi = *(const s16x4*)(eb + row * 68 + c8 + 4);
          short8 o;
          o[0] = lo[0]; o[1] = lo[1]; o[2] = lo[2]; o[3] = lo[3];
          o[4] = hi[0]; o[5] = hi[1]; o[6] = hi[2]; o[7] = hi[3];
          *(short8*)(outb + (size_t)(gr0 + pass * 64 + row) * 1024 + gc0 + c8) = o;
        }
        asm volatile("s_waitcnt lgkmcnt(0)");
        __builtin_amdgcn_sched_barrier(0);
      }
    } else {
      // v part: transpose-bounce -> vT outb2[bt*512+ch][tok]
      int ch0 = gc0 - 1024;
      int bt = m0 >> 10, tok0 = (m0 & 1023) + wm;
#pragma unroll
      for (int pass = 0; pass < 2; ++pass) {
#pragma unroll
        for (int i2 = 0; i2 < 4; ++i2)
#pragma unroll
          for (int j = 0; j < 4; ++j) {
            s16x4 w;
#pragma unroll
            for (int r = 0; r < 4; ++r)
              w[r] = (short)f2bf(acc[pass * 4 + i2][j][r] + bj[j]);
            *(s16x4*)(eb + (j * 16 + lr) * 68 + i2 * 16 + lh * 4) = w;
          }
        asm volatile("s_waitcnt lgkmcnt(0)");
        __builtin_amdgcn_sched_barrier(0);
#pragma unroll
        for (int t = 0; t < 8; ++t) {
          int row = t * 8 + (l >> 3), c8 = (l & 7) * 8;
          s16x4 lo = *(const s16x4*)(eb + row * 68 + c8);
          s16x4 hi = *(const s16x4*)(eb + row * 68 + c8 + 4);
          short8 o;
          o[0] = lo[0]; o[1] = lo[1]; o[2] = lo[2]; o[3] = lo[3];
          o[4] = hi[0]; o[5] = hi[1]; o[6] = hi[2]; o[7] = hi[3];
          *(short8*)(outb2 + (size_t)(bt * 512 + ch0 + row) * 1024 + tok0 + pass * 64 + c8) = o;
        }
        asm volatile("s_waitcnt lgkmcnt(0)");
        __builtin_amdgcn_sched_barrier(0);
      }
    }
  } else if constexpr (MODE == 3 || MODE == 4) {
    u16* obase = (MODE == 3) ? (outb + (size_t)z * 1048576)
                             : (outb + (size_t)(batch0 + z) * 524288);
    const int LD = (MODE == 3) ? 1024 : 512;
#pragma unroll
    for (int pass = 0; pass < 2; ++pass) {
#pragma unroll
      for (int i2 = 0; i2 < 4; ++i2)
#pragma unroll
        for (int j = 0; j < 4; ++j)
#pragma unroll
          for (int r = 0; r < 4; ++r)
            eb[(i2 * 16 + lh * 4 + r) * 68 + j * 16 + lr] =
                f2bf(acc[pass * 4 + i2][j][r]);
      asm volatile("s_waitcnt lgkmcnt(0)");
      __builtin_amdgcn_sched_barrier(0);
#pragma unroll
      for (int t = 0; t < 8; ++t) {
        int row = t * 8 + (l >> 3), c8 = (l & 7) * 8;
        s16x4 lo = *(const s16x4*)(eb + row * 68 + c8);
        s16x4 hi = *(const s16x4*)(eb + row * 68 + c8 + 4);
        short8 o;
        o[0] = lo[0]; o[1] = lo[1]; o[2] = lo[2]; o[3] = lo[3];
        o[4] = hi[0]; o[5] = hi[1]; o[6] = hi[2]; o[7] = hi[3];
        *(short8*)(obase + (size_t)(gr0 + pass * 64 + row) * LD + gc0 + c8) = o;
      }
      asm volatile("s_waitcnt lgkmcnt(0)");
      __builtin_amdgcn_sched_barrier(0);
    }
  } else {  // MODE 2: fp32 out + bias[row] + resid, coalesced float4
    float* ebf = (float*)SH + wid * 2176;  // per-wave [32][68] f32
    int bt = n0 >> 10, nn0 = (n0 & 1023) + wn;
#pragma unroll
    for (int pass = 0; pass < 4; ++pass) {
#pragma unroll
      for (int i2 = 0; i2 < 2; ++i2)
#pragma unroll
        for (int r = 0; r < 4; ++r) {
          float bv = bias[gr0 + pass * 32 + i2 * 16 + lh * 4 + r];
#pragma unroll
          for (int j = 0; j < 4; ++j)
            ebf[(i2 * 16 + lh * 4 + r) * 68 + j * 16 + lr] =
                acc[pass * 2 + i2][j][r] + bv;
        }
      asm volatile("s_waitcnt lgkmcnt(0)");
      __builtin_amdgcn_sched_barrier(0);
#pragma unroll
      for (int t = 0; t < 8; ++t) {
        int row = t * 4 + (l >> 4), c4 = (l & 15) * 4;
        float4 vv = *(const float4*)(ebf + row * 68 + c4);
        size_t addr = ((size_t)bt * 512 + gr0 + pass * 32 + row) * 1024 + nn0 + c4;
        const float4 rr = *(const float4*)(resid + addr);
        vv.x += rr.x; vv.y += rr.y; vv.z += rr.z; vv.w += rr.w;
        *(float4*)(outf + addr) = vv;
      }
      asm volatile("s_waitcnt lgkmcnt(0)");
      __builtin_amdgcn_sched_barrier(0);
    }
  }
#undef STAGE_A
#undef STAGE_B
#undef READ_AF
#undef READ_BF
#undef MFMA_H
#undef PBAR
}

// Distinct kernel names per mode so rocprof dispatches are attributable.
__global__ __launch_bounds__(512, 4) void gemm_qkv(const u16* A, const u16* B, const float* bias,
                                                   u16* outb, u16* outb2, float* outf, const float* resid,
                                                   int Ka, int Kb, int nkt, size_t sA, size_t sB, int b0) {
  gemm_body<5>(A, B, bias, outb, outb2, outf, resid, Ka, Kb, nkt, sA, sB, b0);
}
__global__ __launch_bounds__(512, 4) void gemm_o(const u16* A, const u16* B, const float* bias,
                                                 u16* outb, u16* outb2, float* outf, const float* resid,
                                                 int Ka, int Kb, int nkt, size_t sA, size_t sB, int b0) {
  gemm_body<2>(A, B, bias, outb, outb2, outf, resid, Ka, Kb, nkt, sA, sB, b0);
}
__global__ __launch_bounds__(512, 4) void gemm_s(const u16* A, const u16* B, const float* bias,
                                                 u16* outb, u16* outb2, float* outf, const float* resid,
                                                 int Ka, int Kb, int nkt, size_t sA, size_t sB, int b0) {
  gemm_body<3>(A, B, bias, outb, outb2, outf, resid, Ka, Kb, nkt, sA, sB, b0);
}
__global__ __launch_bounds__(512, 4) void gemm_pv(const u16* A, const u16* B, const float* bias,
                                                  u16* outb, u16* outb2, float* outf, const float* resid,
                                                  int Ka, int Kb, int nkt, size_t sA, size_t sB, int b0) {
  gemm_body<4>(A, B, bias, outb, outb2, outf, resid, Ka, Kb, nkt, sA, sB, b0);
}

// ---------------- in-place row softmax on S (bf16), one wave per row ----------------
__global__ __launch_bounds__(256) void softmax_rows(u16* __restrict__ S) {
  const float scale = 0.04419417382415922f;  // 1/sqrt(512)
  int row = blockIdx.x * 4 + (threadIdx.x >> 6);
  int l = threadIdx.x & 63;
  u16* Sr = S + (size_t)row * 1024;
  short8 a = *(const short8*)(Sr + l * 8);
  short8 b = *(const short8*)(Sr + 512 + l * 8);
  float f[16];
#pragma unroll
  for (int i = 0; i < 8; ++i) { f[i] = bf2f((u16)a[i]); f[8 + i] = bf2f((u16)b[i]); }
  float mx = f[0];
#pragma unroll
  for (int i = 1; i < 16; ++i) mx = fmaxf(mx, f[i]);
#pragma unroll
  for (int d = 1; d < 64; d <<= 1) mx = fmaxf(mx, __shfl_xor(mx, d));
  float s = 0.f;
#pragma unroll
  for (int i = 0; i < 16; ++i) { f[i] = __expf((f[i] - mx) * scale); s += f[i]; }
#pragma unroll
  for (int d = 1; d < 64; d <<= 1) s += __shfl_xor(s, d);
  float inv = 1.f / s;
  short8 oa, ob;
#pragma unroll
  for (int i = 0; i < 8; ++i) { oa[i] = (short)f2bf(f[i] * inv); ob[i] = (short)f2bf(f[8 + i] * inv); }
  *(short8*)(Sr + l * 8) = oa;
  *(short8*)(Sr + 512 + l * 8) = ob;
}

extern "C" void kernel_launch(void* const* d_in, const int* in_sizes, int n_in,
                              void* d_out, int out_size, void* d_ws, size_t ws_size,
                              hipStream_t stream) {
  const float* x   = (const float*)d_in[0];
  const float* gsc = (const float*)d_in[1];
  const float* gbi = (const float*)d_in[2];
  const float* wq  = (const float*)d_in[3];
  const float* bq  = (const float*)d_in[4];
  const float* wk  = (const float*)d_in[5];
  const float* bk  = (const float*)d_in[6];
  const float* wv  = (const float*)d_in[7];
  const float* bv  = (const float*)d_in[8];
  const float* wo  = (const float*)d_in[9];
  const float* bo  = (const float*)d_in[10];

  char* ws = (char*)d_ws;
  u16* wbf = (u16*)ws;                               // 2 MiB: wq,wk,wv,wo bf16
  float* bqkv = (float*)(ws + (2ull << 20));         // 6 KB concat qkv bias
  float* mean_ = (float*)(ws + (2ull << 20) + 65536);
  float* rstd_ = mean_ + 1024;
  u16* h   = (u16*)(ws + (4ull << 20));              // 32 MiB (reused as am)
  u16* qk  = (u16*)(ws + (36ull << 20));             // 64 MiB: [token][q(512)|k(512)]
  u16* vm  = (u16*)(ws + (100ull << 20));            // 32 MiB: vT [b][ch][tok]
  u16* S   = (u16*)(ws + (132ull << 20));            // up to 64 MiB (chunked)
  u16* am  = h;
  float* out = (float*)d_out;

  size_t sbytes = ws_size > (132ull << 20) ? ws_size - (132ull << 20) : 0;
  int CB = 1;
  while (CB < 32 && (size_t)(CB * 2) * (2ull << 20) <= sbytes) CB *= 2;

  wconv<<<1024, 256, 0, stream>>>(wq, wk, wv, wo, bq, bk, bv, wbf, bqkv);
  gn_stats<<<1024, 256, 0, stream>>>(x, mean_, rstd_);
  gn_apply<<<dim3(16, 8, 32), 256, 0, stream>>>(x, mean_, rstd_, gsc, gbi, h);
  // fused q+k+v projection: [q|k] -> qk, v -> vm (transposed), N=1536, K=512 (nkt=16)
  gemm_qkv<<<dim3(6, 128), 512, 0, stream>>>(h, wbf, bqkv, qk, vm, nullptr, nullptr,
                                             512, 512, 16, 0, 0, 0);
  // attention: S = Q K^T ; softmax ; A = P V
  for (int c0 = 0; c0 < 32; c0 += CB) {
    gemm_s<<<dim3(4, 4, CB), 512, 0, stream>>>(qk + (size_t)c0 * 1048576, qk + 512 + (size_t)c0 * 1048576,
                                               nullptr, S, nullptr, nullptr, nullptr,
                                               1024, 1024, 16, 1048576, 1048576, 0);
    softmax_rows<<<CB * 256, 256, 0, stream>>>(S);
    gemm_pv<<<dim3(2, 4, CB), 512, 0, stream>>>(S, vm + (size_t)c0 * 524288,
                                                nullptr, am, nullptr, nullptr, nullptr,
                                                1024, 1024, 32, 1048576, 524288, c0);
  }
  // final projection + residual, K=512 (nkt=16)
  gemm_o<<<dim3(128, 2), 512, 0, stream>>>(wbf + 786432, am, bo, nullptr, nullptr, out, x,
                                           512, 512, 16, 0, 0, 0);
}

// Round 6
// 248.275 us; speedup vs baseline: 5.8257x; 5.8257x over previous
//
#include <hip/hip_runtime.h>
#include <stdint.h>

typedef unsigned short u16;
typedef __attribute__((ext_vector_type(8))) short short8;
typedef __attribute__((ext_vector_type(4))) short s16x4;
typedef __attribute__((ext_vector_type(4))) float f32x4;

#define NTOK 1024
#define CDIM 512
#define NG 32

#define GLOAD_LDS16(gptr, lptr)                                                              \
  __builtin_amdgcn_global_load_lds((const __attribute__((address_space(1))) unsigned int*)(gptr), \
                                   (__attribute__((address_space(3))) unsigned int*)(lptr), 16, 0, 0)

__device__ __forceinline__ u16 f2bf(float f) {
  union { float f; uint32_t u; } v; v.f = f;
  uint32_t r = v.u + 0x7fffu + ((v.u >> 16) & 1u);
  return (u16)(r >> 16);
}

__device__ __forceinline__ float bf2f(u16 b) {
  union { uint32_t u; float f; } v; v.u = ((uint32_t)b) << 16;
  return v.f;
}

// ---------------- weight fp32 -> bf16 (+ concat qkv bias) ----------------
__global__ __launch_bounds__(256) void wconv(const float* __restrict__ wq, const float* __restrict__ wk,
                                             const float* __restrict__ wv, const float* __restrict__ wo,
                                             const float* __restrict__ bq, const float* __restrict__ bk,
                                             const float* __restrict__ bv,
                                             u16* __restrict__ out, float* __restrict__ bqkv) {
  int i = blockIdx.x * 256 + threadIdx.x;
  out[i]          = f2bf(wq[i]);
  out[262144 + i] = f2bf(wk[i]);
  out[524288 + i] = f2bf(wv[i]);
  out[786432 + i] = f2bf(wo[i]);
  if (i < 512) bqkv[i] = bq[i];
  else if (i < 1024) bqkv[i] = bk[i - 512];
  else if (i < 1536) bqkv[i] = bv[i - 1024];
}

// ---------------- GroupNorm stats: one block per (b,g) ----------------
__global__ __launch_bounds__(256) void gn_stats(const float* __restrict__ x,
                                                float* __restrict__ mean_o, float* __restrict__ rstd_o) {
  int bg = blockIdx.x;
  const float4* base = (const float4*)(x + (size_t)bg * 16384);
  float s = 0.f, ss = 0.f;
  for (int i = threadIdx.x; i < 4096; i += 256) {
    float4 v = base[i];
    s  += v.x + v.y + v.z + v.w;
    ss += v.x * v.x + v.y * v.y + v.z * v.z + v.w * v.w;
  }
#pragma unroll
  for (int d = 1; d < 64; d <<= 1) { s += __shfl_xor(s, d); ss += __shfl_xor(ss, d); }
  __shared__ float as[4], as2[4];
  int w = threadIdx.x >> 6;
  if ((threadIdx.x & 63) == 0) { as[w] = s; as2[w] = ss; }
  __syncthreads();
  if (threadIdx.x == 0) {
    float S = as[0] + as[1] + as[2] + as[3];
    float SS = as2[0] + as2[1] + as2[2] + as2[3];
    float m = S * (1.f / 16384.f);
    float var = SS * (1.f / 16384.f) - m * m;
    mean_o[bg] = m;
    rstd_o[bg] = rsqrtf(var + 1e-5f);
  }
}

// ---------------- GN apply + transpose -> h[(b*1024+n)][c] bf16 ----------------
__global__ __launch_bounds__(256) void gn_apply(const float* __restrict__ x,
                                                const float* __restrict__ mean_, const float* __restrict__ rstd_,
                                                const float* __restrict__ gsc, const float* __restrict__ gbi,
                                                u16* __restrict__ h) {
  int n0 = blockIdx.x * 64, c0 = blockIdx.y * 64, b = blockIdx.z;
  __shared__ u16 t[64][65];
  int tid = threadIdx.x;
  int nl4 = (tid & 15) * 4;
  int clb = tid >> 4;
#pragma unroll
  for (int p = 0; p < 4; ++p) {
    int cl = p * 16 + clb;
    int c = c0 + cl;
    int g = c >> 4;
    float m = mean_[b * NG + g], rs = rstd_[b * NG + g];
    float sc = gsc[c] * rs, bi = gbi[c] - m * sc;
    float4 v = *(const float4*)(x + ((size_t)b * CDIM + c) * NTOK + n0 + nl4);
    t[cl][nl4 + 0] = f2bf(v.x * sc + bi);
    t[cl][nl4 + 1] = f2bf(v.y * sc + bi);
    t[cl][nl4 + 2] = f2bf(v.z * sc + bi);
    t[cl][nl4 + 3] = f2bf(v.w * sc + bi);
  }
  __syncthreads();
  int nl = tid >> 3;
  int cc = (tid & 7) * 8;
#pragma unroll
  for (int p = 0; p < 2; ++p) {
    int n = nl + p * 32;
    short8 o;
#pragma unroll
    for (int i = 0; i < 8; ++i) o[i] = (short)t[cc + i][n];
    *(short8*)(h + (size_t)(b * NTOK + n0 + n) * CDIM + c0 + cc) = o;
  }
}

// ------- GEMM 256(M)x128(N) tile, 8 waves (4x2), per-wave 64x64, BK=32, triple-buffer -------
// D[M][N] = A[M][K] * B[N][K]^T, row strides Ka/Kb (u16), K = nkt*32.
// Per-wave acc = 64 f32 (fits AGPR half of the 128-reg unified budget at launch_bounds(512,4))
// -> no spill (round-5 lesson: 128-acc + 128-cap = catastrophic scratch spill) and 2 blocks/CU
// (LDS 72KB x2 = 144 <= 160K). Co-resident block overlaps stage waits + epilogue (m114).
// Triple-buffer schedule per tile t (bc=t%3): stage(t+2)->buf[(t+2)%3] (that buf's reads ended
// at t-1 before its barrier -> race-free); counted vmcnt(3) keeps t+2's loads in flight while
// guaranteeing t+1 landed; ONE barrier per tile.
// Bank spread: 64B rows alias 16 consecutive lanes into 2 slots -> chunk ^= (row>>1)&3 swizzle,
// applied to the pre-swizzled GLOBAL source (LDS dest linear, DMA-legal) and to the ds_read.
// Epilogue: LDS-bounce -> coalesced short8/float4 line stores (round-4 win, reshaped to 64x64).
// MODE 5: fused qkv. gc<1024 -> qk[gr][1024]+gc (+bias); gc>=1024 -> vT outb2[bt][ch][tok] (+bias)
// MODE 2: out fp32 [bt][gr][nn] + bias[gr] + resid   (o proj; M=ch, N=tokens)
// MODE 3: out bf16 [(z*1024+gr)][1024]+gc            (QK^T batched)
// MODE 4: out bf16 [((batch0+z)*1024+gr)][512]+gc    (PV batched)
template <int MODE>
__device__ __forceinline__ void gemm_body(const u16* __restrict__ A, const u16* __restrict__ B,
                                          const float* __restrict__ bias, u16* __restrict__ outb,
                                          u16* __restrict__ outb2,
                                          float* __restrict__ outf, const float* __restrict__ resid,
                                          int Ka, int Kb, int nkt,
                                          size_t strideA, size_t strideB, int batch0) {
  // XCD-chunked bijective swizzle (all launches have nwg % 8 == 0)
  int nx = gridDim.x, ny = gridDim.y;
  int nwg = nx * ny * gridDim.z;
  int id = blockIdx.x + nx * (blockIdx.y + ny * blockIdx.z);
  int cpx = nwg >> 3;
  int sw = (id & 7) * cpx + (id >> 3);
  int bx = sw % nx; int t_ = sw / nx;
  int by = t_ % ny; int z = t_ / ny;

  const u16* Amat = A + (size_t)z * strideA;
  const u16* Bmat = B + (size_t)z * strideB;
  int n0 = bx * 128, m0 = by * 256;
  // 72KB: A bufs [3][256][32] u16 | B bufs [3][128][32] u16 @24576; epilogue reuses as bounce
  __shared__ __align__(16) u16 SH[36864];
  int tid = threadIdx.x;
  int l = tid & 63, wid = tid >> 6;
  int lr = l & 15, lh = l >> 4;
  int wm = (wid >> 1) * 64;      // 4 wave-rows (M)
  int wn = (wid & 1) * 64;       // 2 wave-cols (N)

  f32x4 acc[4][4];
#pragma unroll
  for (int i = 0; i < 4; ++i)
#pragma unroll
    for (int j = 0; j < 4; ++j) acc[i][j] = (f32x4){0.f, 0.f, 0.f, 0.f};

  short8 af[4];
  short8 bfr[4];

  // staging: A 256x32 (16KB) = 2 chunks/thread (rows sr, sr+128); B 128x32 (8KB) = 1 chunk.
  // LDS dest linear (row*32 + sc4*8); global col pre-swizzled by (sr>>1)&3.
  int sr = tid >> 2, sc4 = tid & 3;
  int sg = (sc4 ^ ((sr >> 1) & 3)) * 8;
  const u16* Ag0 = Amat + (size_t)(m0 + sr) * Ka + sg;
  const u16* Ag1 = Ag0 + (size_t)128 * Ka;
  const u16* Bg0 = Bmat + (size_t)(n0 + sr) * Kb + sg;
  u16* Al0 = SH + sr * 32 + sc4 * 8;
  u16* Bl0 = SH + 24576 + sr * 32 + sc4 * 8;

  // per-lane read chunk offset (u16): (lh ^ ((row>>1)&3))*8 with row = 16*frag + lr (base%16==0)
  int rch = (lh ^ ((lr >> 1) & 3)) * 8;

#define STAGE(bufsel, ktv)                                                \
  {                                                                       \
    GLOAD_LDS16(Ag0 + (ktv) * 32, Al0 + (bufsel) * 8192);                 \
    GLOAD_LDS16(Ag1 + (ktv) * 32, Al0 + (bufsel) * 8192 + 4096);          \
    GLOAD_LDS16(Bg0 + (ktv) * 32, Bl0 + (bufsel) * 4096);                 \
  }

#define READ_FRAGS(bufsel)                                                            \
  _Pragma("unroll") for (int i_ = 0; i_ < 4; ++i_)                                    \
    af[i_] = *(const short8*)(SH + (bufsel) * 8192 + (wm + i_ * 16 + lr) * 32 + rch); \
  _Pragma("unroll") for (int j_ = 0; j_ < 4; ++j_)                                    \
    bfr[j_] = *(const short8*)(SH + 24576 + (bufsel) * 4096 + (wn + j_ * 16 + lr) * 32 + rch);

#define MFMA16()                                                                      \
  _Pragma("unroll") for (int i_ = 0; i_ < 4; ++i_)                                    \
    _Pragma("unroll") for (int j_ = 0; j_ < 4; ++j_)                                  \
      acc[i_][j_] = __builtin_amdgcn_mfma_f32_16x16x32_bf16(af[i_], bfr[j_], acc[i_][j_], 0, 0, 0);

  // Prologue: tiles 0,1 staged; wait tile 0 (oldest 3 of 6), tile 1 stays in flight.
  STAGE(0, 0);
  STAGE(1, 1);
  asm volatile("s_waitcnt vmcnt(3)");
  __builtin_amdgcn_sched_barrier(0);
  __builtin_amdgcn_s_barrier();

  int bc = 0, bs = 2;
  for (int t = 0; t < nkt; ++t) {
    const bool more = (t + 2 < nkt);   // uniform
    if (more) STAGE(bs, t + 2);
    READ_FRAGS(bc);
    __builtin_amdgcn_s_setprio(1);
    MFMA16();
    __builtin_amdgcn_s_setprio(0);
    if (more) { asm volatile("s_waitcnt vmcnt(3)"); }
    else      { asm volatile("s_waitcnt vmcnt(0)"); }
    __builtin_amdgcn_sched_barrier(0);
    __builtin_amdgcn_s_barrier();
    bc = (bc == 2) ? 0 : bc + 1;
    bs = (bs == 2) ? 0 : bs + 1;
  }

  // ---------------- epilogue: LDS-bounce -> coalesced line stores ----------------
  __syncthreads();  // K-loop fully done; SH reusable as scratch
  const int gr0 = m0 + wm, gc0 = n0 + wn;
  u16* eb = SH + wid * 4352;             // per-wave [64][68] u16 scratch (8*8704B = 69.6KB)

  if constexpr (MODE == 5) {
    float bj[4];
#pragma unroll
    for (int j = 0; j < 4; ++j) bj[j] = bias[gc0 + j * 16 + lr];
    if (n0 < 1024) {
      // qk part: row-major [32768][1024]
#pragma unroll
      for (int i2 = 0; i2 < 4; ++i2)
#pragma unroll
        for (int j = 0; j < 4; ++j)
#pragma unroll
          for (int r = 0; r < 4; ++r)
            eb[(i2 * 16 + lh * 4 + r) * 68 + j * 16 + lr] = f2bf(acc[i2][j][r] + bj[j]);
      asm volatile("s_waitcnt lgkmcnt(0)");
      __builtin_amdgcn_sched_barrier(0);
#pragma unroll
      for (int t = 0; t < 8; ++t) {
        int row = t * 8 + (l >> 3), c8 = (l & 7) * 8;
        s16x4 lo = *(const s16x4*)(eb + row * 68 + c8);
        s16x4 hi = *(const s16x4*)(eb + row * 68 + c8 + 4);
        short8 o;
        o[0] = lo[0]; o[1] = lo[1]; o[2] = lo[2]; o[3] = lo[3];
        o[4] = hi[0]; o[5] = hi[1]; o[6] = hi[2]; o[7] = hi[3];
        *(short8*)(outb + (size_t)(gr0 + row) * 1024 + gc0 + c8) = o;
      }
    } else {
      // v part: transpose-bounce -> vT outb2[bt*512+ch][tok]
      int ch0 = gc0 - 1024;
      int bt = m0 >> 10, tok0 = (m0 & 1023) + wm;
#pragma unroll
      for (int i2 = 0; i2 < 4; ++i2)
#pragma unroll
        for (int j = 0; j < 4; ++j) {
          s16x4 w;
#pragma unroll
          for (int r = 0; r < 4; ++r) w[r] = (short)f2bf(acc[i2][j][r] + bj[j]);
          *(s16x4*)(eb + (j * 16 + lr) * 68 + i2 * 16 + lh * 4) = w;
        }
      asm volatile("s_waitcnt lgkmcnt(0)");
      __builtin_amdgcn_sched_barrier(0);
#pragma unroll
      for (int t = 0; t < 8; ++t) {
        int row = t * 8 + (l >> 3), c8 = (l & 7) * 8;
        s16x4 lo = *(const s16x4*)(eb + row * 68 + c8);
        s16x4 hi = *(const s16x4*)(eb + row * 68 + c8 + 4);
        short8 o;
        o[0] = lo[0]; o[1] = lo[1]; o[2] = lo[2]; o[3] = lo[3];
        o[4] = hi[0]; o[5] = hi[1]; o[6] = hi[2]; o[7] = hi[3];
        *(short8*)(outb2 + (size_t)(bt * 512 + ch0 + row) * 1024 + tok0 + c8) = o;
      }
    }
  } else if constexpr (MODE == 3 || MODE == 4) {
    u16* obase = (MODE == 3) ? (outb + (size_t)z * 1048576)
                             : (outb + (size_t)(batch0 + z) * 524288);
    const int LD = (MODE == 3) ? 1024 : 512;
#pragma unroll
    for (int i2 = 0; i2 < 4; ++i2)
#pragma unroll
      for (int j = 0; j < 4; ++j)
#pragma unroll
        for (int r = 0; r < 4; ++r)
          eb[(i2 * 16 + lh * 4 + r) * 68 + j * 16 + lr] = f2bf(acc[i2][j][r]);
    asm volatile("s_waitcnt lgkmcnt(0)");
    __builtin_amdgcn_sched_barrier(0);
#pragma unroll
    for (int t = 0; t < 8; ++t) {
      int row = t * 8 + (l >> 3), c8 = (l & 7) * 8;
      s16x4 lo = *(const s16x4*)(eb + row * 68 + c8);
      s16x4 hi = *(const s16x4*)(eb + row * 68 + c8 + 4);
      short8 o;
      o[0] = lo[0]; o[1] = lo[1]; o[2] = lo[2]; o[3] = lo[3];
      o[4] = hi[0]; o[5] = hi[1]; o[6] = hi[2]; o[7] = hi[3];
      *(short8*)(obase + (size_t)(gr0 + row) * LD + gc0 + c8) = o;
    }
  } else {  // MODE 2: fp32 out + bias[row] + resid, coalesced float4
    float* ebf = (float*)SH + wid * 2176;  // per-wave [32][68] f32
    int bt = n0 >> 10, nn0 = (n0 & 1023) + wn;
#pragma unroll
    for (int pass = 0; pass < 2; ++pass) {
#pragma unroll
      for (int i2 = 0; i2 < 2; ++i2)
#pragma unroll
        for (int r = 0; r < 4; ++r) {
          float bv = bias[gr0 + pass * 32 + i2 * 16 + lh * 4 + r];
#pragma unroll
          for (int j = 0; j < 4; ++j)
            ebf[(i2 * 16 + lh * 4 + r) * 68 + j * 16 + lr] = acc[pass * 2 + i2][j][r] + bv;
        }
      asm volatile("s_waitcnt lgkmcnt(0)");
      __builtin_amdgcn_sched_barrier(0);
#pragma unroll
      for (int t = 0; t < 8; ++t) {
        int row = t * 4 + (l >> 4), c4 = (l & 15) * 4;
        float4 vv = *(const float4*)(ebf + row * 68 + c4);
        size_t addr = ((size_t)bt * 512 + gr0 + pass * 32 + row) * 1024 + nn0 + c4;
        const float4 rr = *(const float4*)(resid + addr);
        vv.x += rr.x; vv.y += rr.y; vv.z += rr.z; vv.w += rr.w;
        *(float4*)(outf + addr) = vv;
      }
      asm volatile("s_waitcnt lgkmcnt(0)");
      __builtin_amdgcn_sched_barrier(0);
    }
  }
#undef STAGE
#undef READ_FRAGS
#undef MFMA16
}

// Distinct kernel names per mode so rocprof dispatches are attributable.
__global__ __launch_bounds__(512, 4) void gemm_qkv(const u16* A, const u16* B, const float* bias,
                                                   u16* outb, u16* outb2, float* outf, const float* resid,
                                                   int Ka, int Kb, int nkt, size_t sA, size_t sB, int b0) {
  gemm_body<5>(A, B, bias, outb, outb2, outf, resid, Ka, Kb, nkt, sA, sB, b0);
}
__global__ __launch_bounds__(512, 4) void gemm_o(const u16* A, const u16* B, const float* bias,
                                                 u16* outb, u16* outb2, float* outf, const float* resid,
                                                 int Ka, int Kb, int nkt, size_t sA, size_t sB, int b0) {
  gemm_body<2>(A, B, bias, outb, outb2, outf, resid, Ka, Kb, nkt, sA, sB, b0);
}
__global__ __launch_bounds__(512, 4) void gemm_s(const u16* A, const u16* B, const float* bias,
                                                 u16* outb, u16* outb2, float* outf, const float* resid,
                                                 int Ka, int Kb, int nkt, size_t sA, size_t sB, int b0) {
  gemm_body<3>(A, B, bias, outb, outb2, outf, resid, Ka, Kb, nkt, sA, sB, b0);
}
__global__ __launch_bounds__(512, 4) void gemm_pv(const u16* A, const u16* B, const float* bias,
                                                  u16* outb, u16* outb2, float* outf, const float* resid,
                                                  int Ka, int Kb, int nkt, size_t sA, size_t sB, int b0) {
  gemm_body<4>(A, B, bias, outb, outb2, outf, resid, Ka, Kb, nkt, sA, sB, b0);
}

// ---------------- in-place row softmax on S (bf16), one wave per row ----------------
__global__ __launch_bounds__(256) void softmax_rows(u16* __restrict__ S) {
  const float scale = 0.04419417382415922f;  // 1/sqrt(512)
  int row = blockIdx.x * 4 + (threadIdx.x >> 6);
  int l = threadIdx.x & 63;
  u16* Sr = S + (size_t)row * 1024;
  short8 a = *(const short8*)(Sr + l * 8);
  short8 b = *(const short8*)(Sr + 512 + l * 8);
  float f[16];
#pragma unroll
  for (int i = 0; i < 8; ++i) { f[i] = bf2f((u16)a[i]); f[8 + i] = bf2f((u16)b[i]); }
  float mx = f[0];
#pragma unroll
  for (int i = 1; i < 16; ++i) mx = fmaxf(mx, f[i]);
#pragma unroll
  for (int d = 1; d < 64; d <<= 1) mx = fmaxf(mx, __shfl_xor(mx, d));
  float s = 0.f;
#pragma unroll
  for (int i = 0; i < 16; ++i) { f[i] = __expf((f[i] - mx) * scale); s += f[i]; }
#pragma unroll
  for (int d = 1; d < 64; d <<= 1) s += __shfl_xor(s, d);
  float inv = 1.f / s;
  short8 oa, ob;
#pragma unroll
  for (int i = 0; i < 8; ++i) { oa[i] = (short)f2bf(f[i] * inv); ob[i] = (short)f2bf(f[8 + i] * inv); }
  *(short8*)(Sr + l * 8) = oa;
  *(short8*)(Sr + 512 + l * 8) = ob;
}

extern "C" void kernel_launch(void* const* d_in, const int* in_sizes, int n_in,
                              void* d_out, int out_size, void* d_ws, size_t ws_size,
                              hipStream_t stream) {
  const float* x   = (const float*)d_in[0];
  const float* gsc = (const float*)d_in[1];
  const float* gbi = (const float*)d_in[2];
  const float* wq  = (const float*)d_in[3];
  const float* bq  = (const float*)d_in[4];
  const float* wk  = (const float*)d_in[5];
  const float* bk  = (const float*)d_in[6];
  const float* wv  = (const float*)d_in[7];
  const float* bv  = (const float*)d_in[8];
  const float* wo  = (const float*)d_in[9];
  const float* bo  = (const float*)d_in[10];

  char* ws = (char*)d_ws;
  u16* wbf = (u16*)ws;                               // 2 MiB: wq,wk,wv,wo bf16
  float* bqkv = (float*)(ws + (2ull << 20));         // 6 KB concat qkv bias
  float* mean_ = (float*)(ws + (2ull << 20) + 65536);
  float* rstd_ = mean_ + 1024;
  u16* h   = (u16*)(ws + (4ull << 20));              // 32 MiB (reused as am)
  u16* qk  = (u16*)(ws + (36ull << 20));             // 64 MiB: [token][q(512)|k(512)]
  u16* vm  = (u16*)(ws + (100ull << 20));            // 32 MiB: vT [b][ch][tok]
  u16* S   = (u16*)(ws + (132ull << 20));            // up to 64 MiB (chunked)
  u16* am  = h;
  float* out = (float*)d_out;

  size_t sbytes = ws_size > (132ull << 20) ? ws_size - (132ull << 20) : 0;
  int CB = 1;
  while (CB < 32 && (size_t)(CB * 2) * (2ull << 20) <= sbytes) CB *= 2;

  wconv<<<1024, 256, 0, stream>>>(wq, wk, wv, wo, bq, bk, bv, wbf, bqkv);
  gn_stats<<<1024, 256, 0, stream>>>(x, mean_, rstd_);
  gn_apply<<<dim3(16, 8, 32), 256, 0, stream>>>(x, mean_, rstd_, gsc, gbi, h);
  // fused q+k+v projection: [q|k] -> qk, v -> vm (transposed); tiles 256x128, nkt=16
  gemm_qkv<<<dim3(12, 128), 512, 0, stream>>>(h, wbf, bqkv, qk, vm, nullptr, nullptr,
                                              512, 512, 16, 0, 0, 0);
  // attention: S = Q K^T ; softmax ; A = P V
  for (int c0 = 0; c0 < 32; c0 += CB) {
    gemm_s<<<dim3(8, 4, CB), 512, 0, stream>>>(qk + (size_t)c0 * 1048576, qk + 512 + (size_t)c0 * 1048576,
                                               nullptr, S, nullptr, nullptr, nullptr,
                                               1024, 1024, 16, 1048576, 1048576, 0);
    softmax_rows<<<CB * 256, 256, 0, stream>>>(S);
    gemm_pv<<<dim3(4, 4, CB), 512, 0, stream>>>(S, vm + (size_t)c0 * 524288,
                                                nullptr, am, nullptr, nullptr, nullptr,
                                                1024, 1024, 32, 1048576, 524288, c0);
  }
  // final projection + residual, nkt=16
  gemm_o<<<dim3(256, 2), 512, 0, stream>>>(wbf + 786432, am, bo, nullptr, nullptr, out, x,
                                           512, 512, 16, 0, 0, 0);
}

// Round 7
// 248.152 us; speedup vs baseline: 5.8286x; 1.0005x over previous
//
#include <hip/hip_runtime.h>
#include <stdint.h>

typedef unsigned short u16;
typedef __attribute__((ext_vector_type(8))) short short8;
typedef __attribute__((ext_vector_type(4))) short s16x4;
typedef __attribute__((ext_vector_type(4))) float f32x4;

#define NTOK 1024
#define CDIM 512
#define NG 32

#define GLOAD_LDS16(gptr, lptr)                                                              \
  __builtin_amdgcn_global_load_lds((const __attribute__((address_space(1))) unsigned int*)(gptr), \
                                   (__attribute__((address_space(3))) unsigned int*)(lptr), 16, 0, 0)

__device__ __forceinline__ u16 f2bf(float f) {
  union { float f; uint32_t u; } v; v.f = f;
  uint32_t r = v.u + 0x7fffu + ((v.u >> 16) & 1u);
  return (u16)(r >> 16);
}

__device__ __forceinline__ float bf2f(u16 b) {
  union { uint32_t u; float f; } v; v.u = ((uint32_t)b) << 16;
  return v.f;
}

// ---------------- weight fp32 -> bf16 (+ concat qkv bias) ----------------
__global__ __launch_bounds__(256) void wconv(const float* __restrict__ wq, const float* __restrict__ wk,
                                             const float* __restrict__ wv, const float* __restrict__ wo,
                                             const float* __restrict__ bq, const float* __restrict__ bk,
                                             const float* __restrict__ bv,
                                             u16* __restrict__ out, float* __restrict__ bqkv) {
  int i = blockIdx.x * 256 + threadIdx.x;
  out[i]          = f2bf(wq[i]);
  out[262144 + i] = f2bf(wk[i]);
  out[524288 + i] = f2bf(wv[i]);
  out[786432 + i] = f2bf(wo[i]);
  if (i < 512) bqkv[i] = bq[i];
  else if (i < 1024) bqkv[i] = bk[i - 512];
  else if (i < 1536) bqkv[i] = bv[i - 1024];
}

// ---------------- GroupNorm stats: one block per (b,g) ----------------
__global__ __launch_bounds__(256) void gn_stats(const float* __restrict__ x,
                                                float* __restrict__ mean_o, float* __restrict__ rstd_o) {
  int bg = blockIdx.x;
  const float4* base = (const float4*)(x + (size_t)bg * 16384);
  float s = 0.f, ss = 0.f;
  for (int i = threadIdx.x; i < 4096; i += 256) {
    float4 v = base[i];
    s  += v.x + v.y + v.z + v.w;
    ss += v.x * v.x + v.y * v.y + v.z * v.z + v.w * v.w;
  }
#pragma unroll
  for (int d = 1; d < 64; d <<= 1) { s += __shfl_xor(s, d); ss += __shfl_xor(ss, d); }
  __shared__ float as[4], as2[4];
  int w = threadIdx.x >> 6;
  if ((threadIdx.x & 63) == 0) { as[w] = s; as2[w] = ss; }
  __syncthreads();
  if (threadIdx.x == 0) {
    float S = as[0] + as[1] + as[2] + as[3];
    float SS = as2[0] + as2[1] + as2[2] + as2[3];
    float m = S * (1.f / 16384.f);
    float var = SS * (1.f / 16384.f) - m * m;
    mean_o[bg] = m;
    rstd_o[bg] = rsqrtf(var + 1e-5f);
  }
}

// ---------------- GN apply + transpose -> h[(b*1024+n)][c] bf16 ----------------
__global__ __launch_bounds__(256) void gn_apply(const float* __restrict__ x,
                                                const float* __restrict__ mean_, const float* __restrict__ rstd_,
                                                const float* __restrict__ gsc, const float* __restrict__ gbi,
                                                u16* __restrict__ h) {
  int n0 = blockIdx.x * 64, c0 = blockIdx.y * 64, b = blockIdx.z;
  __shared__ u16 t[64][65];
  int tid = threadIdx.x;
  int nl4 = (tid & 15) * 4;
  int clb = tid >> 4;
#pragma unroll
  for (int p = 0; p < 4; ++p) {
    int cl = p * 16 + clb;
    int c = c0 + cl;
    int g = c >> 4;
    float m = mean_[b * NG + g], rs = rstd_[b * NG + g];
    float sc = gsc[c] * rs, bi = gbi[c] - m * sc;
    float4 v = *(const float4*)(x + ((size_t)b * CDIM + c) * NTOK + n0 + nl4);
    t[cl][nl4 + 0] = f2bf(v.x * sc + bi);
    t[cl][nl4 + 1] = f2bf(v.y * sc + bi);
    t[cl][nl4 + 2] = f2bf(v.z * sc + bi);
    t[cl][nl4 + 3] = f2bf(v.w * sc + bi);
  }
  __syncthreads();
  int nl = tid >> 3;
  int cc = (tid & 7) * 8;
#pragma unroll
  for (int p = 0; p < 2; ++p) {
    int n = nl + p * 32;
    short8 o;
#pragma unroll
    for (int i = 0; i < 8; ++i) o[i] = (short)t[cc + i][n];
    *(short8*)(h + (size_t)(b * NTOK + n0 + n) * CDIM + c0 + cc) = o;
  }
}

// ------- GEMM 256(M)x128(N) tile, 4 waves (2x2), per-wave 128x64, BK=32, triple-buffer -------
// D[M][N] = A[M][K] * B[N][K]^T, row strides Ka/Kb (u16), K = nkt*32.
// Round-6 diagnosis: 64x64/wave @ 16 waves/CU was LDS-READ-BW bound (131 KB ds_read per
// co-resident pair K-step / 85 B/cyc ~ 1540 cyc >> 310 cyc MFMA). LDS traffic/FLOP scales as
// (Mw+Nw)/(Mw*Nw) -> bigger per-wave tile is the lever. 128x64/wave with 4 waves/block keeps
// block tile 256x128, drops traffic to 96 KB/pair-step, and the 128-reg acc is legal because
// 2 blocks x 4 waves = 2 waves/SIMD -> 256-reg budget (launch_bounds(256,2)); round-5's spill
// came from the 128-reg cap at 4 waves/SIMD, not from the acc size itself.
// LDS 72KB -> 2 blocks/CU retained (round-6 overlap win). Triple-buffer, stage(t+2), counted
// vmcnt(6) per step (6 loads/tile: A 4 rows + B 2 rows per thread), one barrier per step.
// Chunk swizzle (both-sides involution): global col chunk ^= (row>>1)&3, LDS dest linear
// (DMA-legal); invariant across a thread's 4 rows (they differ by 64 -> (row>>1)&3 unchanged).
// Epilogue: LDS-bounce -> coalesced short8/float4 line stores (round-4 win, per-wave 128x64).
// MODE 5: fused qkv. gc<1024 -> qk[gr][1024]+gc (+bias); gc>=1024 -> vT outb2[bt][ch][tok] (+bias)
// MODE 2: out fp32 [bt][gr][nn] + bias[gr] + resid   (o proj; M=ch, N=tokens)
// MODE 3: out bf16 [(z*1024+gr)][1024]+gc            (QK^T batched)
// MODE 4: out bf16 [((batch0+z)*1024+gr)][512]+gc    (PV batched)
template <int MODE>
__device__ __forceinline__ void gemm_body(const u16* __restrict__ A, const u16* __restrict__ B,
                                          const float* __restrict__ bias, u16* __restrict__ outb,
                                          u16* __restrict__ outb2,
                                          float* __restrict__ outf, const float* __restrict__ resid,
                                          int Ka, int Kb, int nkt,
                                          size_t strideA, size_t strideB, int batch0) {
  // XCD-chunked bijective swizzle (all launches have nwg % 8 == 0)
  int nx = gridDim.x, ny = gridDim.y;
  int nwg = nx * ny * gridDim.z;
  int id = blockIdx.x + nx * (blockIdx.y + ny * blockIdx.z);
  int cpx = nwg >> 3;
  int sw = (id & 7) * cpx + (id >> 3);
  int bx = sw % nx; int t_ = sw / nx;
  int by = t_ % ny; int z = t_ / ny;

  const u16* Amat = A + (size_t)z * strideA;
  const u16* Bmat = B + (size_t)z * strideB;
  int n0 = bx * 128, m0 = by * 256;
  // 72KB: A bufs [3][256][32] u16 | B bufs [3][128][32] u16 @24576; epilogue reuses as bounce
  __shared__ __align__(16) u16 SH[36864];
  int tid = threadIdx.x;
  int l = tid & 63, wid = tid >> 6;      // 4 waves
  int lr = l & 15, lh = l >> 4;
  int wm = (wid >> 1) * 128;             // 2 wave-rows (M)
  int wn = (wid & 1) * 64;               // 2 wave-cols (N)

  f32x4 acc[8][4];
#pragma unroll
  for (int i = 0; i < 8; ++i)
#pragma unroll
    for (int j = 0; j < 4; ++j) acc[i][j] = (f32x4){0.f, 0.f, 0.f, 0.f};

  short8 af[8];
  short8 bfr[4];

  // staging: A 256x32 (16KB) = 4 chunks/thread (rows sr+{0,64,128,192}); B 128x32 (8KB) = 2
  // chunks/thread (rows sr+{0,64}). LDS dest linear in tid (= tid*16B within each region).
  int sr = tid >> 2, sc4 = tid & 3;
  int sg = (sc4 ^ ((sr >> 1) & 3)) * 8;   // pre-swizzled global col (u16); same for all rows
  const u16* Ag0 = Amat + (size_t)(m0 + sr) * Ka + sg;
  const u16* Bg0 = Bmat + (size_t)(n0 + sr) * Kb + sg;
  u16* Al0 = SH + sr * 32 + sc4 * 8;
  u16* Bl0 = SH + 24576 + sr * 32 + sc4 * 8;

  // per-lane read chunk offset (u16): rows are 16m+lr so (row>>1)&3 == (lr>>1)&3
  int rch = (lh ^ ((lr >> 1) & 3)) * 8;

#define STAGE(bufsel, ktv)                                                        \
  {                                                                               \
    GLOAD_LDS16(Ag0 + (ktv) * 32,                       Al0 + (bufsel) * 8192);   \
    GLOAD_LDS16(Ag0 + (ktv) * 32 + (size_t)64  * Ka,    Al0 + (bufsel) * 8192 + 2048); \
    GLOAD_LDS16(Ag0 + (ktv) * 32 + (size_t)128 * Ka,    Al0 + (bufsel) * 8192 + 4096); \
    GLOAD_LDS16(Ag0 + (ktv) * 32 + (size_t)192 * Ka,    Al0 + (bufsel) * 8192 + 6144); \
    GLOAD_LDS16(Bg0 + (ktv) * 32,                       Bl0 + (bufsel) * 4096);   \
    GLOAD_LDS16(Bg0 + (ktv) * 32 + (size_t)64  * Kb,    Bl0 + (bufsel) * 4096 + 2048); \
  }

#define READ_FRAGS(bufsel)                                                            \
  _Pragma("unroll") for (int i_ = 0; i_ < 8; ++i_)                                    \
    af[i_] = *(const short8*)(SH + (bufsel) * 8192 + (wm + i_ * 16 + lr) * 32 + rch); \
  _Pragma("unroll") for (int j_ = 0; j_ < 4; ++j_)                                    \
    bfr[j_] = *(const short8*)(SH + 24576 + (bufsel) * 4096 + (wn + j_ * 16 + lr) * 32 + rch);

#define MFMA32()                                                                      \
  _Pragma("unroll") for (int i_ = 0; i_ < 8; ++i_)                                    \
    _Pragma("unroll") for (int j_ = 0; j_ < 4; ++j_)                                  \
      acc[i_][j_] = __builtin_amdgcn_mfma_f32_16x16x32_bf16(af[i_], bfr[j_], acc[i_][j_], 0, 0, 0);

  // Prologue: tiles 0,1 staged (12 loads); wait tile 0 (oldest 6), tile 1 stays in flight.
  STAGE(0, 0);
  STAGE(1, 1);
  asm volatile("s_waitcnt vmcnt(6)");
  __builtin_amdgcn_sched_barrier(0);
  __builtin_amdgcn_s_barrier();

  int bc = 0, bs = 2;
  for (int t = 0; t < nkt; ++t) {
    const bool more = (t + 2 < nkt);   // uniform
    if (more) STAGE(bs, t + 2);
    READ_FRAGS(bc);
    __builtin_amdgcn_s_setprio(1);
    MFMA32();
    __builtin_amdgcn_s_setprio(0);
    if (more) { asm volatile("s_waitcnt vmcnt(6)"); }
    else      { asm volatile("s_waitcnt vmcnt(0)"); }
    __builtin_amdgcn_sched_barrier(0);
    __builtin_amdgcn_s_barrier();
    bc = (bc == 2) ? 0 : bc + 1;
    bs = (bs == 2) ? 0 : bs + 1;
  }

  // ---------------- epilogue: LDS-bounce -> coalesced line stores ----------------
  __syncthreads();  // K-loop fully done; SH reusable as scratch
  const int gr0 = m0 + wm, gc0 = n0 + wn;
  u16* eb = SH + wid * 4352;             // per-wave [64][68] u16 scratch (4*8704B = 34.8KB)

  if constexpr (MODE == 5) {
    float bj[4];
#pragma unroll
    for (int j = 0; j < 4; ++j) bj[j] = bias[gc0 + j * 16 + lr];
    if (n0 < 1024) {
      // qk part: row-major [32768][1024]
#pragma unroll
      for (int pass = 0; pass < 2; ++pass) {
#pragma unroll
        for (int i2 = 0; i2 < 4; ++i2)
#pragma unroll
          for (int j = 0; j < 4; ++j)
#pragma unroll
            for (int r = 0; r < 4; ++r)
              eb[(i2 * 16 + lh * 4 + r) * 68 + j * 16 + lr] =
                  f2bf(acc[pass * 4 + i2][j][r] + bj[j]);
        asm volatile("s_waitcnt lgkmcnt(0)");
        __builtin_amdgcn_sched_barrier(0);
#pragma unroll
        for (int t = 0; t < 8; ++t) {
          int row = t * 8 + (l >> 3), c8 = (l & 7) * 8;
          s16x4 lo = *(const s16x4*)(eb + row * 68 + c8);
          s16x4 hi = *(const s16x4*)(eb + row * 68 + c8 + 4);
          short8 o;
          o[0] = lo[0]; o[1] = lo[1]; o[2] = lo[2]; o[3] = lo[3];
          o[4] = hi[0]; o[5] = hi[1]; o[6] = hi[2]; o[7] = hi[3];
          *(short8*)(outb + (size_t)(gr0 + pass * 64 + row) * 1024 + gc0 + c8) = o;
        }
        asm volatile("s_waitcnt lgkmcnt(0)");
        __builtin_amdgcn_sched_barrier(0);
      }
    } else {
      // v part: transpose-bounce -> vT outb2[bt*512+ch][tok]
      int ch0 = gc0 - 1024;
      int bt = m0 >> 10, tok0 = (m0 & 1023) + wm;
#pragma unroll
      for (int pass = 0; pass < 2; ++pass) {
#pragma unroll
        for (int i2 = 0; i2 < 4; ++i2)
#pragma unroll
          for (int j = 0; j < 4; ++j) {
            s16x4 w;
#pragma unroll
            for (int r = 0; r < 4; ++r) w[r] = (short)f2bf(acc[pass * 4 + i2][j][r] + bj[j]);
            *(s16x4*)(eb + (j * 16 + lr) * 68 + i2 * 16 + lh * 4) = w;
          }
        asm volatile("s_waitcnt lgkmcnt(0)");
        __builtin_amdgcn_sched_barrier(0);
#pragma unroll
        for (int t = 0; t < 8; ++t) {
          int row = t * 8 + (l >> 3), c8 = (l & 7) * 8;
          s16x4 lo = *(const s16x4*)(eb + row * 68 + c8);
          s16x4 hi = *(const s16x4*)(eb + row * 68 + c8 + 4);
          short8 o;
          o[0] = lo[0]; o[1] = lo[1]; o[2] = lo[2]; o[3] = lo[3];
          o[4] = hi[0]; o[5] = hi[1]; o[6] = hi[2]; o[7] = hi[3];
          *(short8*)(outb2 + (size_t)(bt * 512 + ch0 + row) * 1024 + tok0 + pass * 64 + c8) = o;
        }
        asm volatile("s_waitcnt lgkmcnt(0)");
        __builtin_amdgcn_sched_barrier(0);
      }
    }
  } else if constexpr (MODE == 3 || MODE == 4) {
    u16* obase = (MODE == 3) ? (outb + (size_t)z * 1048576)
                             : (outb + (size_t)(batch0 + z) * 524288);
    const int LD = (MODE == 3) ? 1024 : 512;
#pragma unroll
    for (int pass = 0; pass < 2; ++pass) {
#pragma unroll
      for (int i2 = 0; i2 < 4; ++i2)
#pragma unroll
        for (int j = 0; j < 4; ++j)
#pragma unroll
          for (int r = 0; r < 4; ++r)
            eb[(i2 * 16 + lh * 4 + r) * 68 + j * 16 + lr] = f2bf(acc[pass * 4 + i2][j][r]);
      asm volatile("s_waitcnt lgkmcnt(0)");
      __builtin_amdgcn_sched_barrier(0);
#pragma unroll
      for (int t = 0; t < 8; ++t) {
        int row = t * 8 + (l >> 3), c8 = (l & 7) * 8;
        s16x4 lo = *(const s16x4*)(eb + row * 68 + c8);
        s16x4 hi = *(const s16x4*)(eb + row * 68 + c8 + 4);
        short8 o;
        o[0] = lo[0]; o[1] = lo[1]; o[2] = lo[2]; o[3] = lo[3];
        o[4] = hi[0]; o[5] = hi[1]; o[6] = hi[2]; o[7] = hi[3];
        *(short8*)(obase + (size_t)(gr0 + pass * 64 + row) * LD + gc0 + c8) = o;
      }
      asm volatile("s_waitcnt lgkmcnt(0)");
      __builtin_amdgcn_sched_barrier(0);
    }
  } else {  // MODE 2: fp32 out + bias[row] + resid, coalesced float4
    float* ebf = (float*)SH + wid * 2176;  // per-wave [32][68] f32
    int bt = n0 >> 10, nn0 = (n0 & 1023) + wn;
#pragma unroll
    for (int pass = 0; pass < 4; ++pass) {
#pragma unroll
      for (int i2 = 0; i2 < 2; ++i2)
#pragma unroll
        for (int r = 0; r < 4; ++r) {
          float bv = bias[gr0 + pass * 32 + i2 * 16 + lh * 4 + r];
#pragma unroll
          for (int j = 0; j < 4; ++j)
            ebf[(i2 * 16 + lh * 4 + r) * 68 + j * 16 + lr] = acc[pass * 2 + i2][j][r] + bv;
        }
      asm volatile("s_waitcnt lgkmcnt(0)");
      __builtin_amdgcn_sched_barrier(0);
#pragma unroll
      for (int t = 0; t < 8; ++t) {
        int row = t * 4 + (l >> 4), c4 = (l & 15) * 4;
        float4 vv = *(const float4*)(ebf + row * 68 + c4);
        size_t addr = ((size_t)bt * 512 + gr0 + pass * 32 + row) * 1024 + nn0 + c4;
        const float4 rr = *(const float4*)(resid + addr);
        vv.x += rr.x; vv.y += rr.y; vv.z += rr.z; vv.w += rr.w;
        *(float4*)(outf + addr) = vv;
      }
      asm volatile("s_waitcnt lgkmcnt(0)");
      __builtin_amdgcn_sched_barrier(0);
    }
  }
#undef STAGE
#undef READ_FRAGS
#undef MFMA32
}

// Distinct kernel names per mode so rocprof dispatches are attributable.
__global__ __launch_bounds__(256, 2) void gemm_qkv(const u16* A, const u16* B, const float* bias,
                                                   u16* outb, u16* outb2, float* outf, const float* resid,
                                                   int Ka, int Kb, int nkt, size_t sA, size_t sB, int b0) {
  gemm_body<5>(A, B, bias, outb, outb2, outf, resid, Ka, Kb, nkt, sA, sB, b0);
}
__global__ __launch_bounds__(256, 2) void gemm_o(const u16* A, const u16* B, const float* bias,
                                                 u16* outb, u16* outb2, float* outf, const float* resid,
                                                 int Ka, int Kb, int nkt, size_t sA, size_t sB, int b0) {
  gemm_body<2>(A, B, bias, outb, outb2, outf, resid, Ka, Kb, nkt, sA, sB, b0);
}
__global__ __launch_bounds__(256, 2) void gemm_s(const u16* A, const u16* B, const float* bias,
                                                 u16* outb, u16* outb2, float* outf, const float* resid,
                                                 int Ka, int Kb, int nkt, size_t sA, size_t sB, int b0) {
  gemm_body<3>(A, B, bias, outb, outb2, outf, resid, Ka, Kb, nkt, sA, sB, b0);
}
__global__ __launch_bounds__(256, 2) void gemm_pv(const u16* A, const u16* B, const float* bias,
                                                  u16* outb, u16* outb2, float* outf, const float* resid,
                                                  int Ka, int Kb, int nkt, size_t sA, size_t sB, int b0) {
  gemm_body<4>(A, B, bias, outb, outb2, outf, resid, Ka, Kb, nkt, sA, sB, b0);
}

// ---------------- in-place row softmax on S (bf16), one wave per row ----------------
__global__ __launch_bounds__(256) void softmax_rows(u16* __restrict__ S) {
  const float scale = 0.04419417382415922f;  // 1/sqrt(512)
  int row = blockIdx.x * 4 + (threadIdx.x >> 6);
  int l = threadIdx.x & 63;
  u16* Sr = S + (size_t)row * 1024;
  short8 a = *(const short8*)(Sr + l * 8);
  short8 b = *(const short8*)(Sr + 512 + l * 8);
  float f[16];
#pragma unroll
  for (int i = 0; i < 8; ++i) { f[i] = bf2f((u16)a[i]); f[8 + i] = bf2f((u16)b[i]); }
  float mx = f[0];
#pragma unroll
  for (int i = 1; i < 16; ++i) mx = fmaxf(mx, f[i]);
#pragma unroll
  for (int d = 1; d < 64; d <<= 1) mx = fmaxf(mx, __shfl_xor(mx, d));
  float s = 0.f;
#pragma unroll
  for (int i = 0; i < 16; ++i) { f[i] = __expf((f[i] - mx) * scale); s += f[i]; }
#pragma unroll
  for (int d = 1; d < 64; d <<= 1) s += __shfl_xor(s, d);
  float inv = 1.f / s;
  short8 oa, ob;
#pragma unroll
  for (int i = 0; i < 8; ++i) { oa[i] = (short)f2bf(f[i] * inv); ob[i] = (short)f2bf(f[8 + i] * inv); }
  *(short8*)(Sr + l * 8) = oa;
  *(short8*)(Sr + 512 + l * 8) = ob;
}

extern "C" void kernel_launch(void* const* d_in, const int* in_sizes, int n_in,
                              void* d_out, int out_size, void* d_ws, size_t ws_size,
                              hipStream_t stream) {
  const float* x   = (const float*)d_in[0];
  const float* gsc = (const float*)d_in[1];
  const float* gbi = (const float*)d_in[2];
  const float* wq  = (const float*)d_in[3];
  const float* bq  = (const float*)d_in[4];
  const float* wk  = (const float*)d_in[5];
  const float* bk  = (const float*)d_in[6];
  const float* wv  = (const float*)d_in[7];
  const float* bv  = (const float*)d_in[8];
  const float* wo  = (const float*)d_in[9];
  const float* bo  = (const float*)d_in[10];

  char* ws = (char*)d_ws;
  u16* wbf = (u16*)ws;                               // 2 MiB: wq,wk,wv,wo bf16
  float* bqkv = (float*)(ws + (2ull << 20));         // 6 KB concat qkv bias
  float* mean_ = (float*)(ws + (2ull << 20) + 65536);
  float* rstd_ = mean_ + 1024;
  u16* h   = (u16*)(ws + (4ull << 20));              // 32 MiB (reused as am)
  u16* qk  = (u16*)(ws + (36ull << 20));             // 64 MiB: [token][q(512)|k(512)]
  u16* vm  = (u16*)(ws + (100ull << 20));            // 32 MiB: vT [b][ch][tok]
  u16* S   = (u16*)(ws + (132ull << 20));            // up to 64 MiB (chunked)
  u16* am  = h;
  float* out = (float*)d_out;

  size_t sbytes = ws_size > (132ull << 20) ? ws_size - (132ull << 20) : 0;
  int CB = 1;
  while (CB < 32 && (size_t)(CB * 2) * (2ull << 20) <= sbytes) CB *= 2;

  wconv<<<1024, 256, 0, stream>>>(wq, wk, wv, wo, bq, bk, bv, wbf, bqkv);
  gn_stats<<<1024, 256, 0, stream>>>(x, mean_, rstd_);
  gn_apply<<<dim3(16, 8, 32), 256, 0, stream>>>(x, mean_, rstd_, gsc, gbi, h);
  // fused q+k+v projection: [q|k] -> qk, v -> vm (transposed); tiles 256x128, nkt=16
  gemm_qkv<<<dim3(12, 128), 256, 0, stream>>>(h, wbf, bqkv, qk, vm, nullptr, nullptr,
                                              512, 512, 16, 0, 0, 0);
  // attention: S = Q K^T ; softmax ; A = P V
  for (int c0 = 0; c0 < 32; c0 += CB) {
    gemm_s<<<dim3(8, 4, CB), 256, 0, stream>>>(qk + (size_t)c0 * 1048576, qk + 512 + (size_t)c0 * 1048576,
                                               nullptr, S, nullptr, nullptr, nullptr,
                                               1024, 1024, 16, 1048576, 1048576, 0);
    softmax_rows<<<CB * 256, 256, 0, stream>>>(S);
    gemm_pv<<<dim3(4, 4, CB), 256, 0, stream>>>(S, vm + (size_t)c0 * 524288,
                                                nullptr, am, nullptr, nullptr, nullptr,
                                                1024, 1024, 32, 1048576, 524288, c0);
  }
  // final projection + residual, nkt=16
  gemm_o<<<dim3(256, 2), 256, 0, stream>>>(wbf + 786432, am, bo, nullptr, nullptr, out, x,
                                           512, 512, 16, 0, 0, 0);
}